// Round 2
// baseline (411.857 us; speedup 1.0000x reference)
//
#include <hip/hip_runtime.h>

#define TT 32
#define NN 4096
#define BETA 0.75f

// ---------------- transpose inp [T][N] -> XT [N][T] ----------------
__global__ void k_transpose(const float* __restrict__ inp, float* __restrict__ xt) {
    int j = blockIdx.x * blockDim.x + threadIdx.x;
    if (j >= NN) return;
#pragma unroll
    for (int t = 0; t < TT; ++t) xt[j * TT + t] = inp[t * NN + j];
}

// ---------------- skinny GEMM: Cp[s][t][i] = sum_{j in Kslice s} W[i][j] * XT[j][t]
// lane = (t4 = lane>>4, k4 = lane&15). Per iteration each lane:
//   - loads float4 of W along k for 4 rows   (wave: 64 consecutive k / quarter)
//   - loads x[j0..j0+3][t4*8 .. t4*8+7]      (8 float4)
//   - 128 FMAs (4 rows x 4 k x 8 t)
// grid = (rowblocks=256, S=4), block = 256 (4 waves x 4 rows = 16 rows/block)
__global__ __launch_bounds__(256, 4) void k_gemm(const float* __restrict__ W,
                                                 const float* __restrict__ xt,
                                                 float* __restrict__ Cp) {
    const int wave = threadIdx.x >> 6;
    const int lane = threadIdx.x & 63;
    const int k4 = lane & 15;
    const int t4 = lane >> 4;
    const int r0 = blockIdx.x * 16 + wave * 4;
    const int s = blockIdx.y;
    const int jbase = s * 1024;

    float acc[4][8];
#pragma unroll
    for (int r = 0; r < 4; ++r)
#pragma unroll
        for (int q = 0; q < 8; ++q) acc[r][q] = 0.f;

    for (int kc = 0; kc < 16; ++kc) {
        const int j0 = jbase + kc * 64 + k4 * 4;

        float4 wv[4];
#pragma unroll
        for (int r = 0; r < 4; ++r)
            wv[r] = *reinterpret_cast<const float4*>(W + (size_t)(r0 + r) * NN + j0);

        float4 xa[4], xb[4];
#pragma unroll
        for (int e = 0; e < 4; ++e) {
            const float* xrow = xt + (size_t)(j0 + e) * TT + t4 * 8;
            xa[e] = *reinterpret_cast<const float4*>(xrow);
            xb[e] = *reinterpret_cast<const float4*>(xrow + 4);
        }

#define ROW_E(r, WC, e)                       \
        acc[r][0] += wv[r].WC * xa[e].x;      \
        acc[r][1] += wv[r].WC * xa[e].y;      \
        acc[r][2] += wv[r].WC * xa[e].z;      \
        acc[r][3] += wv[r].WC * xa[e].w;      \
        acc[r][4] += wv[r].WC * xb[e].x;      \
        acc[r][5] += wv[r].WC * xb[e].y;      \
        acc[r][6] += wv[r].WC * xb[e].z;      \
        acc[r][7] += wv[r].WC * xb[e].w;

#define ROW_ALL(r) ROW_E(r, x, 0) ROW_E(r, y, 1) ROW_E(r, z, 2) ROW_E(r, w, 3)

        ROW_ALL(0)
        ROW_ALL(1)
        ROW_ALL(2)
        ROW_ALL(3)
#undef ROW_ALL
#undef ROW_E
    }

    // reduce across the 16 k4 lanes (stays within 16-lane groups)
#pragma unroll
    for (int r = 0; r < 4; ++r)
#pragma unroll
        for (int q = 0; q < 8; ++q) {
            float v = acc[r][q];
            v += __shfl_xor(v, 1);
            v += __shfl_xor(v, 2);
            v += __shfl_xor(v, 4);
            v += __shfl_xor(v, 8);
            acc[r][q] = v;
        }

    if (k4 == 0) {
        float* outp = Cp + (size_t)s * TT * NN;
#pragma unroll
        for (int r = 0; r < 4; ++r)
#pragma unroll
            for (int q = 0; q < 8; ++q) {
                const int t = t4 * 8 + q;
                outp[t * NN + r0 + r] = acc[r][q];
            }
    }
}

// ---------------- LIF scan for a hidden layer ----------------
__global__ void k_lif_hidden(const float* __restrict__ Cp,
                             float* __restrict__ memhis,    // d_out + 320 + layer*NN
                             float* __restrict__ spkT,      // [NN][TT] for next GEMM
                             float* __restrict__ spk_row) { // [TT][NN]
    const int i = blockIdx.x * blockDim.x + threadIdx.x;
    if (i >= NN) return;
    float mem = 0.f;
#pragma unroll
    for (int t = 0; t < TT; ++t) {
        const float cur = Cp[t * NN + i]
                        + Cp[1 * TT * NN + t * NN + i]
                        + Cp[2 * TT * NN + t * NN + i]
                        + Cp[3 * TT * NN + t * NN + i];
        mem = BETA * mem + cur;
        const float spk = (mem > 1.0f) ? 1.0f : 0.0f;
        mem -= spk;                    // THRESH = 1.0
        memhis[t * (3 * NN) + i] = mem;
        spkT[i * TT + t] = spk;
        spk_row[t * NN + i] = spk;
    }
}

// ---------------- output GEMV: curo[t][o] = dot(out_w[o], spk_row[t]) ----------------
__global__ void k_out_gemv(const float* __restrict__ out_w,
                           const float* __restrict__ spk_row,
                           float* __restrict__ curo) {
    const int t = blockIdx.x;
    const int tid = threadIdx.x;
    float acc[10];
#pragma unroll
    for (int o = 0; o < 10; ++o) acc[o] = 0.f;
    for (int j = tid; j < NN; j += 256) {
        const float x = spk_row[t * NN + j];
#pragma unroll
        for (int o = 0; o < 10; ++o) acc[o] += out_w[o * NN + j] * x;
    }
    __shared__ float red[10][256];
#pragma unroll
    for (int o = 0; o < 10; ++o) red[o][tid] = acc[o];
    __syncthreads();
    for (int st = 128; st > 0; st >>= 1) {
        if (tid < st) {
#pragma unroll
            for (int o = 0; o < 10; ++o) red[o][tid] += red[o][tid + st];
        }
        __syncthreads();
    }
    if (tid < 10) curo[t * 10 + tid] = red[tid][0];
}

// ---------------- output LIF scan ----------------
__global__ void k_lif_out(const float* __restrict__ curo, float* __restrict__ out_spks) {
    const int o = threadIdx.x;
    if (o >= 10) return;
    float mem = 0.f;
    for (int t = 0; t < TT; ++t) {
        mem = BETA * mem + curo[t * 10 + o];
        const float spk = (mem > 1.0f) ? 1.0f : 0.0f;
        mem -= spk;
        out_spks[t * 10 + o] = spk;
    }
}

extern "C" void kernel_launch(void* const* d_in, const int* in_sizes, int n_in,
                              void* d_out, int out_size, void* d_ws, size_t ws_size,
                              hipStream_t stream) {
    const float* inp  = (const float*)d_in[0];
    const float* fc0  = (const float*)d_in[1];
    const float* fc1  = (const float*)d_in[2];
    const float* fc2  = (const float*)d_in[3];
    const float* outw = (const float*)d_in[4];
    float* out = (float*)d_out;

    float* ws = (float*)d_ws;
    float* XT_A    = ws;                  // 131072 floats  [NN][TT]
    float* XT_B    = ws + 131072;         // 131072
    float* spk_row = ws + 262144;         // 131072  [TT][NN]
    float* curo    = ws + 393216;         // 320
    float* Cp      = ws + 393536;         // 4 * 32 * 4096 = 524288 partials

    float* memh0 = out + 320;             // mem_his[t][0][i] at 320 + t*3*NN + 0*NN + i
    float* memh1 = out + 320 + NN;
    float* memh2 = out + 320 + 2 * NN;

    k_transpose<<<16, 256, 0, stream>>>(inp, XT_A);

    k_gemm<<<dim3(256, 4), 256, 0, stream>>>(fc0, XT_A, Cp);
    k_lif_hidden<<<32, 128, 0, stream>>>(Cp, memh0, XT_B, spk_row);

    k_gemm<<<dim3(256, 4), 256, 0, stream>>>(fc1, XT_B, Cp);
    k_lif_hidden<<<32, 128, 0, stream>>>(Cp, memh1, XT_A, spk_row);

    k_gemm<<<dim3(256, 4), 256, 0, stream>>>(fc2, XT_A, Cp);
    k_lif_hidden<<<32, 128, 0, stream>>>(Cp, memh2, XT_B, spk_row);

    k_out_gemv<<<32, 256, 0, stream>>>(outw, spk_row, curo);
    k_lif_out<<<1, 64, 0, stream>>>(curo, out);
}

// Round 5
// 278.412 us; speedup vs baseline: 1.4793x; 1.4793x over previous
//
#include <hip/hip_runtime.h>

#define TT 32
#define NN 4096
#define BETA 0.75f

typedef __attribute__((ext_vector_type(8))) short short8;
typedef __attribute__((ext_vector_type(4))) float f32x4;
typedef unsigned int u32;
typedef unsigned short u16;

__device__ __forceinline__ u16 f2bf_rne(float f) {
    u32 u = __float_as_uint(f);
    u += 0x7FFFu + ((u >> 16) & 1u);
    return (u16)(u >> 16);
}

// f ≈ hf + mf + lf (each bf16); |err| <= 2^-23 |f|
__device__ __forceinline__ void split3(float f, short& h, short& m, short& l) {
    u32 u = __float_as_uint(f);
    h = (short)(u >> 16);
    float hf = __uint_as_float(u & 0xFFFF0000u);
    float r = f - hf;                         // exact
    u32 ur = __float_as_uint(r);
    u32 um = ur + (0x7FFFu + ((ur >> 16) & 1u));
    m = (short)(um >> 16);
    float mf = __uint_as_float(um & 0xFFFF0000u);
    l = (short)f2bf_rne(r - mf);              // r - mf exact (Sterbenz)
}

// ---------------- split inp [T][IN] f32 -> 3x bf16 ----------------
__global__ void k_split_inp(const float* __restrict__ inp, u16* __restrict__ h,
                            u16* __restrict__ m, u16* __restrict__ l) {
    const int base = (blockIdx.x * blockDim.x + threadIdx.x) * 8;
    float4 a0 = *reinterpret_cast<const float4*>(inp + base);
    float4 a1 = *reinterpret_cast<const float4*>(inp + base + 4);
    float av[8] = {a0.x, a0.y, a0.z, a0.w, a1.x, a1.y, a1.z, a1.w};
    short8 vh, vm, vl;
#pragma unroll
    for (int j = 0; j < 8; ++j) {
        short hh, mm, ll; split3(av[j], hh, mm, ll);
        vh[j] = hh; vm[j] = mm; vl[j] = ll;
    }
    *reinterpret_cast<short8*>(h + base) = vh;
    *reinterpret_cast<short8*>(m + base) = vm;
    *reinterpret_cast<short8*>(l + base) = vl;
}

// ---------------- MFMA GEMM: Cp[s][t][i] = sum_k W[i][k]*B[t][k] ----------------
// A frag (16x16x32 bf16): lane l holds A[row=l&15][k=(l>>4)*8+j], j=0..7 (contiguous)
// B frag: lane l holds B[k=(l>>4)*8+j][col=l&15]; C/D: row=(l>>4)*4+r, col=l&15 (m89)
template <bool SPLIT_B>
__global__ __launch_bounds__(256) void k_gemm(const float* __restrict__ W,
                                              const u16* __restrict__ Bh,
                                              const u16* __restrict__ Bm,
                                              const u16* __restrict__ Bl,
                                              float* __restrict__ Cp, int kchunks) {
    const int wave = threadIdx.x >> 6;
    const int lane = threadIdx.x & 63;
    const int l15 = lane & 15;
    const int l4 = lane >> 4;
    const int r0 = (blockIdx.x * 4 + wave) * 16;
    const int s = blockIdx.y;
    const int kb0 = s * kchunks * 32;

    const float* Wp = W + (size_t)(r0 + l15) * NN + kb0 + l4 * 8;
    const size_t boff = (size_t)l15 * NN + kb0 + l4 * 8;

    f32x4 acc0 = {0.f, 0.f, 0.f, 0.f};
    f32x4 acc1 = {0.f, 0.f, 0.f, 0.f};

#pragma unroll 2
    for (int kc = 0; kc < kchunks; ++kc) {
        const int off = kc * 32;
        float4 a0 = *reinterpret_cast<const float4*>(Wp + off);
        float4 a1 = *reinterpret_cast<const float4*>(Wp + off + 4);
        short8 BH0 = *reinterpret_cast<const short8*>(Bh + boff + off);
        short8 BH1 = *reinterpret_cast<const short8*>(Bh + boff + 16 * NN + off);

        float av[8] = {a0.x, a0.y, a0.z, a0.w, a1.x, a1.y, a1.z, a1.w};
        short8 AH, AM, AL;
#pragma unroll
        for (int j = 0; j < 8; ++j) {
            short hh, mm, ll; split3(av[j], hh, mm, ll);
            AH[j] = hh; AM[j] = mm; AL[j] = ll;
        }

        if (SPLIT_B) {
            short8 BM0 = *reinterpret_cast<const short8*>(Bm + boff + off);
            short8 BM1 = *reinterpret_cast<const short8*>(Bm + boff + 16 * NN + off);
            short8 BL0 = *reinterpret_cast<const short8*>(Bl + boff + off);
            short8 BL1 = *reinterpret_cast<const short8*>(Bl + boff + 16 * NN + off);
            // small terms first
            acc0 = __builtin_amdgcn_mfma_f32_16x16x32_bf16(AH, BL0, acc0, 0, 0, 0);
            acc0 = __builtin_amdgcn_mfma_f32_16x16x32_bf16(AM, BM0, acc0, 0, 0, 0);
            acc0 = __builtin_amdgcn_mfma_f32_16x16x32_bf16(AL, BH0, acc0, 0, 0, 0);
            acc0 = __builtin_amdgcn_mfma_f32_16x16x32_bf16(AM, BH0, acc0, 0, 0, 0);
            acc0 = __builtin_amdgcn_mfma_f32_16x16x32_bf16(AH, BM0, acc0, 0, 0, 0);
            acc0 = __builtin_amdgcn_mfma_f32_16x16x32_bf16(AH, BH0, acc0, 0, 0, 0);
            acc1 = __builtin_amdgcn_mfma_f32_16x16x32_bf16(AH, BL1, acc1, 0, 0, 0);
            acc1 = __builtin_amdgcn_mfma_f32_16x16x32_bf16(AM, BM1, acc1, 0, 0, 0);
            acc1 = __builtin_amdgcn_mfma_f32_16x16x32_bf16(AL, BH1, acc1, 0, 0, 0);
            acc1 = __builtin_amdgcn_mfma_f32_16x16x32_bf16(AM, BH1, acc1, 0, 0, 0);
            acc1 = __builtin_amdgcn_mfma_f32_16x16x32_bf16(AH, BM1, acc1, 0, 0, 0);
            acc1 = __builtin_amdgcn_mfma_f32_16x16x32_bf16(AH, BH1, acc1, 0, 0, 0);
        } else {
            acc0 = __builtin_amdgcn_mfma_f32_16x16x32_bf16(AL, BH0, acc0, 0, 0, 0);
            acc0 = __builtin_amdgcn_mfma_f32_16x16x32_bf16(AM, BH0, acc0, 0, 0, 0);
            acc0 = __builtin_amdgcn_mfma_f32_16x16x32_bf16(AH, BH0, acc0, 0, 0, 0);
            acc1 = __builtin_amdgcn_mfma_f32_16x16x32_bf16(AL, BH1, acc1, 0, 0, 0);
            acc1 = __builtin_amdgcn_mfma_f32_16x16x32_bf16(AM, BH1, acc1, 0, 0, 0);
            acc1 = __builtin_amdgcn_mfma_f32_16x16x32_bf16(AH, BH1, acc1, 0, 0, 0);
        }
    }

    float* outp = Cp + (size_t)s * TT * NN;
    const int row = r0 + l4 * 4;
#pragma unroll
    for (int r = 0; r < 4; ++r) {
        outp[(size_t)l15 * NN + row + r] = acc0[r];
        outp[(size_t)(l15 + 16) * NN + row + r] = acc1[r];
    }
}

// ---------------- sum K-split partials: cur[t][i] = sum_s Cp[s][t][i] ----------------
__global__ void k_sum(const float* __restrict__ Cp, int S, float* __restrict__ cur) {
    const int idx = (blockIdx.x * 256 + threadIdx.x) * 4;
    float4 a = *reinterpret_cast<const float4*>(Cp + idx);
    for (int s = 1; s < S; ++s) {
        float4 b = *reinterpret_cast<const float4*>(Cp + (size_t)s * TT * NN + idx);
        a.x += b.x; a.y += b.y; a.z += b.z; a.w += b.w;
    }
    *reinterpret_cast<float4*>(cur + idx) = a;
}

// ---------------- LIF scan over t ----------------
__global__ void k_scan(const float* __restrict__ cur,
                       float* __restrict__ memh,   // stride 3*NN
                       u16* __restrict__ spk) {    // [TT][NN] bf16
    const int i = blockIdx.x * 64 + threadIdx.x;
    float mem = 0.f;
#pragma unroll
    for (int t = 0; t < TT; ++t) {
        mem = BETA * mem + cur[(size_t)t * NN + i];
        const bool sp = mem > 1.0f;
        mem -= sp ? 1.0f : 0.0f;
        memh[(size_t)t * (3 * NN) + i] = mem;
        spk[(size_t)t * NN + i] = sp ? 0x3F80u : 0u;
    }
}

// ---------------- output GEMV over bf16 spikes ----------------
__global__ void k_out_gemv(const float* __restrict__ out_w,
                           const u16* __restrict__ spk,
                           float* __restrict__ curo) {
    const int t = blockIdx.x;
    const int tid = threadIdx.x;
    float acc[10];
#pragma unroll
    for (int o = 0; o < 10; ++o) acc[o] = 0.f;
    for (int j = tid; j < NN; j += 256) {
        const float x = spk[(size_t)t * NN + j] ? 1.0f : 0.0f;
#pragma unroll
        for (int o = 0; o < 10; ++o) acc[o] += out_w[(size_t)o * NN + j] * x;
    }
    __shared__ float red[10][256];
#pragma unroll
    for (int o = 0; o < 10; ++o) red[o][tid] = acc[o];
    __syncthreads();
    for (int st = 128; st > 0; st >>= 1) {
        if (tid < st) {
#pragma unroll
            for (int o = 0; o < 10; ++o) red[o][tid] += red[o][tid + st];
        }
        __syncthreads();
    }
    if (tid < 10) curo[t * 10 + tid] = red[tid][0];
}

// ---------------- output LIF scan ----------------
__global__ void k_lif_out(const float* __restrict__ curo, float* __restrict__ out_spks) {
    const int o = threadIdx.x;
    if (o >= 10) return;
    float mem = 0.f;
    for (int t = 0; t < TT; ++t) {
        mem = BETA * mem + curo[t * 10 + o];
        const float spk = (mem > 1.0f) ? 1.0f : 0.0f;
        mem -= spk;
        out_spks[t * 10 + o] = spk;
    }
}

extern "C" void kernel_launch(void* const* d_in, const int* in_sizes, int n_in,
                              void* d_out, int out_size, void* d_ws, size_t ws_size,
                              hipStream_t stream) {
    const float* inp  = (const float*)d_in[0];
    const float* fc0  = (const float*)d_in[1];
    const float* fc1  = (const float*)d_in[2];
    const float* fc2  = (const float*)d_in[3];
    const float* outw = (const float*)d_in[4];
    float* out = (float*)d_out;

    const size_t plane_f = (size_t)TT * NN;            // 131072
    auto need = [&](int S) {
        return plane_f * 4 * S       // Cp
             + plane_f * 4           // cur
             + plane_f * 2 * 2       // spkA/spkB
             + plane_f * 2 * 3       // inp h/m/l
             + 2048;
    };
    int S = (ws_size >= need(16)) ? 16
          : (ws_size >= need(8))  ? 8
          : (ws_size >= need(4))  ? 4
          : (ws_size >= need(2))  ? 2 : 1;
    const int kchunks = 128 / S;

    char* w = (char*)d_ws;
    float* Cp  = (float*)w;            w += plane_f * 4 * S;
    float* cur = (float*)w;            w += plane_f * 4;
    u16* spkA  = (u16*)w;              w += plane_f * 2;
    u16* spkB  = (u16*)w;              w += plane_f * 2;
    u16* inph  = (u16*)w;              w += plane_f * 2;
    u16* inpm  = (u16*)w;              w += plane_f * 2;
    u16* inpl  = (u16*)w;              w += plane_f * 2;
    float* curo = (float*)w;

    float* memh0 = out + 320;
    float* memh1 = out + 320 + NN;
    float* memh2 = out + 320 + 2 * NN;

    k_split_inp<<<64, 256, 0, stream>>>(inp, inph, inpm, inpl);

    k_gemm<true><<<dim3(64, S), 256, 0, stream>>>(fc0, inph, inpm, inpl, Cp, kchunks);
    k_sum<<<128, 256, 0, stream>>>(Cp, S, cur);
    k_scan<<<64, 64, 0, stream>>>(cur, memh0, spkA);

    k_gemm<false><<<dim3(64, S), 256, 0, stream>>>(fc1, spkA, nullptr, nullptr, Cp, kchunks);
    k_sum<<<128, 256, 0, stream>>>(Cp, S, cur);
    k_scan<<<64, 64, 0, stream>>>(cur, memh1, spkB);

    k_gemm<false><<<dim3(64, S), 256, 0, stream>>>(fc2, spkB, nullptr, nullptr, Cp, kchunks);
    k_sum<<<128, 256, 0, stream>>>(Cp, S, cur);
    k_scan<<<64, 64, 0, stream>>>(cur, memh2, spkA);

    k_out_gemv<<<32, 256, 0, stream>>>(outw, spkA, curo);
    k_lif_out<<<1, 64, 0, stream>>>(curo, out);
}